// Round 8
// baseline (19.500 us; speedup 1.0000x reference)
//
#include <hip/hip_runtime.h>
#include <hip/hip_bf16.h>

// MahalanobisClassifier, fused single dispatch, 32x32 wave tiles,
// A-fragments register-resident (both 16-row sub-tiles), B' LDS re-reads
// halved vs the 16x64-wave version: each ds_read_b128 of B feeds 2 MFMAs.
// out[b,c] = -( sum_d x^2*w - 2 sum_d x*(p*w) + s[c] ),  w = exp(ld)
// bf16 MFMA GEMM, K=512 concat: A'=[x^2 | x], B'=[w | -2*p*w], s in epilogue.
//
// Block: 512 threads (8 waves = 4 row-groups x 2 col-halves), tile 128x64,
// grid (16,16) = 256 blocks = 1/CU. Only B' (64 KB) goes through LDS; ONE
// barrier. Per-output accumulation order identical to the R5/R7 baseline
// (dual accS/accR chains, same kt order) -> bitwise-identical results.

#define C_N 1000
#define D_N 256

typedef __attribute__((ext_vector_type(8))) short bf16x8;
typedef __attribute__((ext_vector_type(4))) float f32x4;

__device__ inline bf16x8 pack8(const float* v) {
  union { bf16x8 o; __hip_bfloat162 h[4]; } u;
#pragma unroll
  for (int j = 0; j < 4; ++j)
    u.h[j] = __float22bfloat162_rn(make_float2(v[2 * j], v[2 * j + 1]));
  return u.o;
}

__global__ __launch_bounds__(512, 2) void mahal_fused(
    const float* __restrict__ x, const float* __restrict__ p,
    const float* __restrict__ ld, float* __restrict__ out) {
  __shared__ short lB[4][16][64][8];   // 64 KB: 4 class-tiles x 16 ktiles, frag order
  __shared__ float s_lds[2][64];

  const int tid = threadIdx.x;
  const int w   = tid >> 6;        // wave 0..7
  const int l   = tid & 63;
  const int r16 = l & 15;
  const int hi  = l >> 4;
  const int bx  = blockIdx.x;      // rows bx*128..+127
  const int by  = blockIdx.y;      // cols by*64..+63

  // ---------------- B' prep: waves split (class-tile, d-half) [as R5/R7] ----------------
  {
    const int ct = w & 3;          // class-tile 0..3
    const int dh = w >> 2;         // d-half 0..1
    const int c  = by * 64 + ct * 16 + r16;
    const bool valid = (c < C_N);
    float sp = 0.f;
#pragma unroll
    for (int t = 0; t < 4; ++t) {
      const int d = dh * 128 + t * 32 + hi * 8;
      float wv[8], pwv[8];
      if (valid) {
        const float* lp = ld + (size_t)c * D_N + d;
        const float* pp = p  + (size_t)c * D_N + d;
        float4 l0 = *reinterpret_cast<const float4*>(lp);
        float4 l1 = *reinterpret_cast<const float4*>(lp + 4);
        float4 p0 = *reinterpret_cast<const float4*>(pp);
        float4 p1 = *reinterpret_cast<const float4*>(pp + 4);
        float lv[8] = {l0.x,l0.y,l0.z,l0.w,l1.x,l1.y,l1.z,l1.w};
        float pv[8] = {p0.x,p0.y,p0.z,p0.w,p1.x,p1.y,p1.z,p1.w};
#pragma unroll
        for (int j = 0; j < 8; ++j) {
          float wj = __expf(lv[j]);
          wv[j]  = wj;
          pwv[j] = -2.f * pv[j] * wj;
          sp += pv[j] * pv[j] * wj;
        }
      } else {
#pragma unroll
        for (int j = 0; j < 8; ++j) { wv[j] = 0.f; pwv[j] = 0.f; }
      }
      *reinterpret_cast<bf16x8*>(&lB[ct][dh * 4 + t][l][0])     = pack8(wv);
      *reinterpret_cast<bf16x8*>(&lB[ct][8 + dh * 4 + t][l][0]) = pack8(pwv);
    }
    sp += __shfl_xor(sp, 16, 64);
    sp += __shfl_xor(sp, 32, 64);
    if (l < 16) s_lds[dh][ct * 16 + r16] = sp;
  }

  // ---------------- A' prep: 32 rows (2 sub-tiles) straight into registers ----------------
  const int wm = w >> 1;           // row-group 0..3
  const int wn = w & 1;            // col-half 0..1
  bf16x8 aSq[2][8], aRaw[2][8];
#pragma unroll
  for (int mt = 0; mt < 2; ++mt) {
    const int row = bx * 128 + wm * 32 + mt * 16 + r16;
#pragma unroll
    for (int t = 0; t < 8; ++t) {
      const int d = t * 32 + hi * 8;
      const float* xp = x + (size_t)row * D_N + d;
      float4 v0 = *reinterpret_cast<const float4*>(xp);
      float4 v1 = *reinterpret_cast<const float4*>(xp + 4);
      float v[8] = {v0.x,v0.y,v0.z,v0.w,v1.x,v1.y,v1.z,v1.w};
      float sq[8];
#pragma unroll
      for (int j = 0; j < 8; ++j) sq[j] = v[j] * v[j];
      aSq[mt][t]  = pack8(sq);
      aRaw[mt][t] = pack8(v);
    }
  }
  __syncthreads();   // B' + s visible; the ONLY barrier

  // ---------------- compute: wave tile 32x32, each B read feeds 2 MFMAs ----------------
  f32x4 accS[2][2], accR[2][2];
#pragma unroll
  for (int mt = 0; mt < 2; ++mt)
#pragma unroll
    for (int n = 0; n < 2; ++n) { accS[mt][n] = {0.f,0.f,0.f,0.f}; accR[mt][n] = {0.f,0.f,0.f,0.f}; }

#pragma unroll
  for (int kt = 0; kt < 8; ++kt) {
#pragma unroll
    for (int n = 0; n < 2; ++n) {
      bf16x8 b0 = *reinterpret_cast<const bf16x8*>(&lB[wn * 2 + n][kt][l][0]);
      bf16x8 b1 = *reinterpret_cast<const bf16x8*>(&lB[wn * 2 + n][8 + kt][l][0]);
#pragma unroll
      for (int mt = 0; mt < 2; ++mt) {
        accS[mt][n] = __builtin_amdgcn_mfma_f32_16x16x32_bf16(aSq[mt][kt],  b0, accS[mt][n], 0, 0, 0);
        accR[mt][n] = __builtin_amdgcn_mfma_f32_16x16x32_bf16(aRaw[mt][kt], b1, accR[mt][n], 0, 0, 0);
      }
    }
  }

  // ---------------- epilogue ----------------
  // C/D layout: col = lane&15, row = (lane>>4)*4 + reg   [verified R1-R7]
#pragma unroll
  for (int mt = 0; mt < 2; ++mt) {
    const int rowbase = bx * 128 + wm * 32 + mt * 16 + hi * 4;
#pragma unroll
    for (int n = 0; n < 2; ++n) {
      const int col = by * 64 + wn * 32 + n * 16 + r16;
      if (col < C_N) {
        const int ci = wn * 32 + n * 16 + r16;
        const float sc = s_lds[0][ci] + s_lds[1][ci];
#pragma unroll
        for (int r = 0; r < 4; ++r)
          out[(size_t)(rowbase + r) * C_N + col] = -(accS[mt][n][r] + accR[mt][n][r] + sc);
      }
    }
  }
}

extern "C" void kernel_launch(void* const* d_in, const int* in_sizes, int n_in,
                              void* d_out, int out_size, void* d_ws, size_t ws_size,
                              hipStream_t stream) {
  const float* x  = (const float*)d_in[0];
  const float* p  = (const float*)d_in[1];
  const float* ld = (const float*)d_in[2];
  float* out = (float*)d_out;
  mahal_fused<<<dim3(16, 16), 512, 0, stream>>>(x, p, ld, out);
}

// Round 9
// 16.253 us; speedup vs baseline: 1.1998x; 1.1998x over previous
//
#include <hip/hip_runtime.h>
#include <hip/hip_bf16.h>

// MahalanobisClassifier, fused single dispatch, A-fragments register-resident.
// out[b,c] = -( sum_d x^2*w - 2 sum_d x*(p*w) + s[c] ),  w = exp(ld)
// bf16 MFMA GEMM, K=512 concat: A'=[x^2 | x], B'=[w | -2*p*w], s in epilogue.
//
// Block: 512 threads (8 waves), tile 128 rows x 64 classes, grid (16,16).
// Wave w owns output rows w*16..+15 (full 64 cols): its A' fragments are packed
// directly into VGPRs during prep (prep lane layout == MFMA A-frag layout:
// lane l -> row l&15, k (l>>4)*8+j — verified R1-R8). Only B' (64 KB) goes
// through LDS; ONE barrier; phase 0 (x^2 vs w) and phase 1 (x vs -2pw)
// interleave into dual accumulator chains with no intermediate sync.
//
// Measured-best configuration (16.07/16.09 µs, R5/R7). Perturbations that
// REGRESS it, kept as comments so they aren't retried:
//  - R3: finer grid w/ redundant B-prep (+2.6 µs)
//  - R6: hoisting all 32 global loads above the VALU chain (+1.0 µs, VGPR)
//  - R8: 32x32 wave tile w/ 128-VGPR A-frags, halved B LDS reads (+3.4 µs)
//    => LDS B-reads are NOT the critical path at 2 waves/SIMD.

#define C_N 1000
#define D_N 256

typedef __attribute__((ext_vector_type(8))) short bf16x8;
typedef __attribute__((ext_vector_type(4))) float f32x4;

__device__ inline bf16x8 pack8(const float* v) {
  union { bf16x8 o; __hip_bfloat162 h[4]; } u;
#pragma unroll
  for (int j = 0; j < 4; ++j)
    u.h[j] = __float22bfloat162_rn(make_float2(v[2 * j], v[2 * j + 1]));
  return u.o;
}

__global__ __launch_bounds__(512, 2) void mahal_fused(
    const float* __restrict__ x, const float* __restrict__ p,
    const float* __restrict__ ld, float* __restrict__ out) {
  __shared__ short lB[4][16][64][8];   // 64 KB: 4 class-tiles x 16 ktiles, frag order
  __shared__ float s_lds[2][64];

  const int tid = threadIdx.x;
  const int w   = tid >> 6;        // wave 0..7
  const int l   = tid & 63;
  const int r16 = l & 15;
  const int hi  = l >> 4;
  const int bx  = blockIdx.x;      // rows bx*128..+127
  const int by  = blockIdx.y;      // cols by*64..+63

  // ---------------- B' prep: waves split (class-tile, d-half) ----------------
  {
    const int ct = w & 3;          // class-tile 0..3
    const int dh = w >> 2;         // d-half 0..1
    const int c  = by * 64 + ct * 16 + r16;
    const bool valid = (c < C_N);
    float sp = 0.f;
#pragma unroll
    for (int t = 0; t < 4; ++t) {
      const int d = dh * 128 + t * 32 + hi * 8;
      float wv[8], pwv[8];
      if (valid) {
        const float* lp = ld + (size_t)c * D_N + d;
        const float* pp = p  + (size_t)c * D_N + d;
        float4 l0 = *reinterpret_cast<const float4*>(lp);
        float4 l1 = *reinterpret_cast<const float4*>(lp + 4);
        float4 p0 = *reinterpret_cast<const float4*>(pp);
        float4 p1 = *reinterpret_cast<const float4*>(pp + 4);
        float lv[8] = {l0.x,l0.y,l0.z,l0.w,l1.x,l1.y,l1.z,l1.w};
        float pv[8] = {p0.x,p0.y,p0.z,p0.w,p1.x,p1.y,p1.z,p1.w};
#pragma unroll
        for (int j = 0; j < 8; ++j) {
          float wj = __expf(lv[j]);
          wv[j]  = wj;
          pwv[j] = -2.f * pv[j] * wj;
          sp += pv[j] * pv[j] * wj;
        }
      } else {
#pragma unroll
        for (int j = 0; j < 8; ++j) { wv[j] = 0.f; pwv[j] = 0.f; }
      }
      *reinterpret_cast<bf16x8*>(&lB[ct][dh * 4 + t][l][0])     = pack8(wv);
      *reinterpret_cast<bf16x8*>(&lB[ct][8 + dh * 4 + t][l][0]) = pack8(pwv);
    }
    sp += __shfl_xor(sp, 16, 64);
    sp += __shfl_xor(sp, 32, 64);
    if (l < 16) s_lds[dh][ct * 16 + r16] = sp;
  }

  // ---------------- A' prep: straight into registers (frag order) ----------------
  bf16x8 aSq[8], aRaw[8];
  {
    const int row = bx * 128 + w * 16 + r16;   // wave w owns row-tile w
#pragma unroll
    for (int t = 0; t < 8; ++t) {
      const int d = t * 32 + hi * 8;
      const float* xp = x + (size_t)row * D_N + d;
      float4 v0 = *reinterpret_cast<const float4*>(xp);
      float4 v1 = *reinterpret_cast<const float4*>(xp + 4);
      float v[8] = {v0.x,v0.y,v0.z,v0.w,v1.x,v1.y,v1.z,v1.w};
      float sq[8];
#pragma unroll
      for (int j = 0; j < 8; ++j) sq[j] = v[j] * v[j];
      aSq[t]  = pack8(sq);
      aRaw[t] = pack8(v);
    }
  }
  __syncthreads();   // B' + s visible; the ONLY barrier

  // ---------------- compute: wave tile 16x64, dual phase-interleaved acc ----------------
  f32x4 acc0[4], acc1[4];
#pragma unroll
  for (int n = 0; n < 4; ++n) { acc0[n] = {0.f,0.f,0.f,0.f}; acc1[n] = {0.f,0.f,0.f,0.f}; }

#pragma unroll
  for (int kt = 0; kt < 8; ++kt) {
#pragma unroll
    for (int n = 0; n < 4; ++n) {
      bf16x8 b0 = *reinterpret_cast<const bf16x8*>(&lB[n][kt][l][0]);
      bf16x8 b1 = *reinterpret_cast<const bf16x8*>(&lB[n][8 + kt][l][0]);
      acc0[n] = __builtin_amdgcn_mfma_f32_16x16x32_bf16(aSq[kt],  b0, acc0[n], 0, 0, 0);
      acc1[n] = __builtin_amdgcn_mfma_f32_16x16x32_bf16(aRaw[kt], b1, acc1[n], 0, 0, 0);
    }
  }

  // ---------------- epilogue ----------------
  // C/D layout: col = lane&15, row = (lane>>4)*4 + reg   [verified R1-R8]
  const int rowbase = bx * 128 + w * 16 + hi * 4;
#pragma unroll
  for (int n = 0; n < 4; ++n) {
    const int col = by * 64 + n * 16 + r16;
    if (col < C_N) {
      const int ci = n * 16 + r16;
      const float sc = s_lds[0][ci] + s_lds[1][ci];
#pragma unroll
      for (int r = 0; r < 4; ++r)
        out[(size_t)(rowbase + r) * C_N + col] = -(acc0[n][r] + acc1[n][r] + sc);
    }
  }
}

extern "C" void kernel_launch(void* const* d_in, const int* in_sizes, int n_in,
                              void* d_out, int out_size, void* d_ws, size_t ws_size,
                              hipStream_t stream) {
  const float* x  = (const float*)d_in[0];
  const float* p  = (const float*)d_in[1];
  const float* ld = (const float*)d_in[2];
  float* out = (float*)d_out;
  mahal_fused<<<dim3(16, 16), 512, 0, stream>>>(x, p, ld, out);
}